// Round 2
// baseline (3717.838 us; speedup 1.0000x reference)
//
#include <hip/hip_runtime.h>

typedef _Float16 f16;
typedef _Float16 f16x8 __attribute__((ext_vector_type(8)));
typedef _Float16 f16x4 __attribute__((ext_vector_type(4)));
typedef float    f32x4 __attribute__((ext_vector_type(4)));

#define TPB 256

// ---------------------------------------------------------------------------
// Prologue: fused normalize -> per-channel pixel permutation -> space_to_depth
// Output layout: A0[p][c] fp16, p = b*1024 + h2*32 + w2 (8192 px), c = 0..191
// ---------------------------------------------------------------------------
__global__ __launch_bounds__(TPB) void prologue_k(
    const float* __restrict__ x, const float* __restrict__ mu,
    const float* __restrict__ sigma, const int* __restrict__ perm,
    f16* __restrict__ A0)
{
    int gid = blockIdx.x * TPB + threadIdx.x;
    if (gid >= 8192 * 192) return;
    int c = gid % 192;
    int p = gid / 192;
    int b  = p >> 10;
    int h2 = (p >> 5) & 31;
    int w2 = p & 31;
    int cc = c >> 6;
    int bh = (c >> 3) & 7;
    int bw = c & 7;
    int j   = (h2 * 8 + bh) * 256 + (w2 * 8 + bw);
    int src = perm[cc * 65536 + j];
    float v = (x[(b * 3 + cc) * 65536 + src] - mu[cc]) / sigma[cc];
    A0[gid] = (f16)v;
}

// ---------------------------------------------------------------------------
// Weight conversion, coalesced: thread <-> (o,i); reads 9 consecutive fp32
// (L1 absorbs the per-instruction stride), writes 9 contiguous-2B sweeps.
// ---------------------------------------------------------------------------
__global__ __launch_bounds__(TPB) void wconv_k(const float* __restrict__ wf,
                                               f16* __restrict__ wh)
{
    int c   = blockIdx.y;            // conv 0..191
    int s   = c % 6;
    int s3  = s % 3;
    int ic  = (s3 == 0) ? 96 : 128;
    int ocv = (s3 == 2) ? 96 : 128;
    int wo  = (s3 == 0 ? 0 : (s3 == 1 ? 110592 : 258048)) + (s >= 3 ? 368640 : 0);
    int n   = ocv * ic;
    int idx = blockIdx.x * TPB + threadIdx.x;
    if (idx >= n) return;
    int o, i;
    if (ic == 128) { o = idx >> 7; i = idx & 127; }
    else           { o = idx / 96; i = idx - o * 96; }
    size_t base = (size_t)(c / 6) * 737280 + wo;
    const float* src = &wf[base + ((size_t)o * ic + i) * 9];
    float v[9];
#pragma unroll
    for (int t = 0; t < 9; ++t) v[t] = src[t];
#pragma unroll
    for (int t = 0; t < 9; ++t) wh[base + (size_t)t * n + idx] = (f16)v[t];
}

__global__ __launch_bounds__(TPB) void mconv_k(const float* __restrict__ mf,
                                               f16* __restrict__ mh, int n)
{
    int i = blockIdx.x * TPB + threadIdx.x;
    if (i < n) mh[i] = (f16)mf[i];
}

// biases fp32, pre-scaled by 2^-block (704 biases per block)
__global__ __launch_bounds__(TPB) void bconv_k(const float* __restrict__ bf,
                                               float* __restrict__ bs, int n)
{
    int i = blockIdx.x * TPB + threadIdx.x;
    if (i < n) bs[i] = ldexpf(bf[i], -(i / 704));
}

// ---------------------------------------------------------------------------
// Per-image barrier (32 WGs). Counter monotonically increases; agent-scope
// release/acquire fences make H-buffer writes visible across XCDs (correct
// regardless of workgroup->XCD placement).
// ---------------------------------------------------------------------------
__device__ __forceinline__ void img_barrier(unsigned* __restrict__ bar, int img,
                                            unsigned target)
{
    __syncthreads();
    if (threadIdx.x == 0) {
        __builtin_amdgcn_fence(__ATOMIC_RELEASE, "agent");
        __hip_atomic_fetch_add(&bar[img * 32], 1u, __ATOMIC_RELAXED,
                               __HIP_MEMORY_SCOPE_AGENT);
        while (__hip_atomic_load(&bar[img * 32], __ATOMIC_RELAXED,
                                 __HIP_MEMORY_SCOPE_AGENT) < target)
            __builtin_amdgcn_s_sleep(1);
        __builtin_amdgcn_fence(__ATOMIC_ACQUIRE, "agent");
    }
    __syncthreads();
}

// ---------------------------------------------------------------------------
// One conv / 1x1-mix layer as a device function (same math as the verified
// round-1 kernel). local = 0..31 within the image; unit = (rowtile, octile).
// W tap t+1 is register-prefetched during tap t's MFMAs (T14 async split).
// ---------------------------------------------------------------------------
template<int IC, int OC, int TAPS, bool RELU, bool ACCUM, bool OUT32>
__device__ void conv_layer(f16* lds, int img, int local,
    const f16* __restrict__ Xin, int ICS,
    const f16* __restrict__ W, const float* __restrict__ bias,
    f16* __restrict__ Out, int OCS, float* __restrict__ Out32, float scale)
{
    constexpr int NC8   = IC / 8;
    constexpr int PAD   = (TAPS == 9) ? 1 : 0;
    constexpr int ROWS  = 4 + 2 * PAD;
    constexpr int WW    = 32 + 2 * PAD;
    constexpr int UNITS = 8 * (OC / 32);
    constexpr int CNT   = 32 * NC8;      // f16x8 elements per W tap slice

    f16* Alds = lds + ROWS * NC8 * WW * 8;
    const int tid  = threadIdx.x;
    const int r0   = (local & 7) * 4;
    const int lane = tid & 63, wave = tid >> 6, lq = lane >> 4, ln = lane & 15;

    for (int rnd = 0; rnd < ((UNITS > 32) ? 2 : 1); ++rnd) {
        const int u = local + rnd * 32;
        if (u >= UNITS) break;
        const int oc0 = (u >> 3) * 32;

        if (rnd == 0) {
            // ---- stage X tile (+halo) ----
            for (int i = tid; i < ROWS * WW * NC8; i += TPB) {
                int c8  = i % NC8;
                int rem = i / NC8;
                int wv  = rem % WW;
                int ri  = rem / WW;
                int row = r0 - PAD + ri;
                int wc  = wv - PAD;
                f16x8 v = {};
                if ((unsigned)row < 32u && (unsigned)wc < 32u) {
                    int p = img * 1024 + row * 32 + wc;
                    v = *(const f16x8*)&Xin[(size_t)p * ICS + c8 * 8];
                }
                *(f16x8*)&lds[((ri * NC8 + c8) * WW + wv) * 8] = v;
            }
        } else {
            __syncthreads();   // previous round done reading Alds
        }
        // ---- stage W tap 0: [c8][oc_local][8] ----
        for (int i = tid; i < CNT; i += TPB) {
            int o = i & 31, c8 = i >> 5;
            *(f16x8*)&Alds[(c8 * 32 + o) * 8] =
                *(const f16x8*)&W[((size_t)oc0 + o) * IC + c8 * 8];
        }
        __syncthreads();

        f32x4 acc[2][2] = {};
        for (int tap = 0; tap < TAPS; ++tap) {
            // prefetch next tap's W slice into registers (latency hides
            // under this tap's MFMAs)
            f16x8 w0v = {}, w1v = {};
            if (TAPS == 9 && tap + 1 < TAPS) {
                const f16* Wn = &W[((size_t)(tap + 1) * OC + oc0) * IC];
                { int i = tid;
                  w0v = *(const f16x8*)&Wn[(size_t)(i & 31) * IC + (i >> 5) * 8]; }
                if (CNT > 256) { int i = tid + 256; if (i < CNT)
                  w1v = *(const f16x8*)&Wn[(size_t)(i & 31) * IC + (i >> 5) * 8]; }
            }
            const int dy = (TAPS == 9) ? tap / 3 - 1 : 0;
            const int dx = (TAPS == 9) ? tap % 3 - 1 : 0;
            const int bb = ((wave + PAD + dy) * NC8 * WW + (ln + dx + PAD)) * 8;
#pragma unroll
            for (int kc = 0; kc < IC / 32; ++kc) {
                f16x8 a0 = *(const f16x8*)&Alds[((kc * 4 + lq) * 32 + ln) * 8];
                f16x8 a1 = *(const f16x8*)&Alds[((kc * 4 + lq) * 32 + 16 + ln) * 8];
                f16x8 b0 = *(const f16x8*)&lds[bb + (kc * 4 + lq) * WW * 8];
                f16x8 b1 = *(const f16x8*)&lds[bb + (kc * 4 + lq) * WW * 8 + 128];
                acc[0][0] = __builtin_amdgcn_mfma_f32_16x16x32_f16(a0, b0, acc[0][0], 0, 0, 0);
                acc[1][0] = __builtin_amdgcn_mfma_f32_16x16x32_f16(a1, b0, acc[1][0], 0, 0, 0);
                acc[0][1] = __builtin_amdgcn_mfma_f32_16x16x32_f16(a0, b1, acc[0][1], 0, 0, 0);
                acc[1][1] = __builtin_amdgcn_mfma_f32_16x16x32_f16(a1, b1, acc[1][1], 0, 0, 0);
            }
            if (TAPS == 9 && tap + 1 < TAPS) {
                __syncthreads();   // everyone done reading Alds[tap]
                { int i = tid;
                  *(f16x8*)&Alds[((i >> 5) * 32 + (i & 31)) * 8] = w0v; }
                if (CNT > 256) { int i = tid + 256; if (i < CNT)
                  *(f16x8*)&Alds[((i >> 5) * 32 + (i & 31)) * 8] = w1v; }
                __syncthreads();   // Alds[tap+1] ready
            }
        }

        // ---- epilogue ----
        const int prow = r0 + wave;
#pragma unroll
        for (int mm = 0; mm < 2; ++mm) {
#pragma unroll
            for (int nn = 0; nn < 2; ++nn) {
                int oc = oc0 + mm * 16 + lq * 4;
                int p  = img * 1024 + prow * 32 + nn * 16 + ln;
                float b0 = 0.f, b1 = 0.f, b2 = 0.f, b3 = 0.f;
                if (TAPS == 9) {
                    float4 bv = *(const float4*)&bias[oc];
                    b0 = bv.x; b1 = bv.y; b2 = bv.z; b3 = bv.w;
                }
                float v0 = acc[mm][nn][0] * scale + b0;
                float v1 = acc[mm][nn][1] * scale + b1;
                float v2 = acc[mm][nn][2] * scale + b2;
                float v3 = acc[mm][nn][3] * scale + b3;
                if (RELU) {
                    v0 = fmaxf(v0, 0.f); v1 = fmaxf(v1, 0.f);
                    v2 = fmaxf(v2, 0.f); v3 = fmaxf(v3, 0.f);
                }
                if (OUT32) {
                    size_t ob = (size_t)(img * 192 + oc) * 1024 + prow * 32 + nn * 16 + ln;
                    Out32[ob]        = v0;
                    Out32[ob + 1024] = v1;
                    Out32[ob + 2048] = v2;
                    Out32[ob + 3072] = v3;
                } else {
                    f16* op = &Out[(size_t)p * OCS + oc];
                    if (ACCUM) {
                        f16x4 old = *(const f16x4*)op;
                        v0 += (float)old[0]; v1 += (float)old[1];
                        v2 += (float)old[2]; v3 += (float)old[3];
                    }
                    f16x4 hv;
                    hv[0] = (f16)v0; hv[1] = (f16)v1; hv[2] = (f16)v2; hv[3] = (f16)v3;
                    *(f16x4*)op = hv;
                }
            }
        }
    }
}

// ---------------------------------------------------------------------------
// Persistent kernel: the whole 32-block program, per-image barriers between
// layers. 256 WGs; image = wg&7 (XCD-pinned locality), local = wg>>3.
// ---------------------------------------------------------------------------
__global__ __launch_bounds__(TPB) void persist_k(
    const f16* __restrict__ WH, const f16* __restrict__ MH,
    const float* __restrict__ BS, f16* __restrict__ XA, f16* __restrict__ XB,
    f16* __restrict__ H1, f16* __restrict__ H2, float* __restrict__ out,
    unsigned* __restrict__ bar)
{
    extern __shared__ f16 lds[];
    const int wg    = blockIdx.x;
    const int img   = wg & 7;
    const int local = wg >> 3;
    unsigned gen = 0;

    for (int blk = 0; blk < 32; ++blk) {
        const size_t w0 = (size_t)blk * 737280;
        const size_t b0 = (size_t)blk * 704;
        f16* cur = (blk & 1) ? XB : XA;
        f16* nxt = (blk & 1) ? XA : XB;

        conv_layer<96, 128, 9, true, false, false>(lds, img, local, cur + 96, 192,
            WH + w0 + 0,      BS + b0 + 0,   H1, 128, nullptr, 1.f);
        img_barrier(bar, img, ++gen * 32u);
        conv_layer<128, 128, 9, true, false, false>(lds, img, local, H1, 128,
            WH + w0 + 110592, BS + b0 + 128, H2, 128, nullptr, 1.f);
        img_barrier(bar, img, ++gen * 32u);
        conv_layer<128, 96, 9, false, true, false>(lds, img, local, H2, 128,
            WH + w0 + 258048, BS + b0 + 256, cur, 192, nullptr, 1.f);
        img_barrier(bar, img, ++gen * 32u);
        conv_layer<96, 128, 9, true, false, false>(lds, img, local, cur, 192,
            WH + w0 + 368640, BS + b0 + 352, H1, 128, nullptr, 1.f);
        img_barrier(bar, img, ++gen * 32u);
        conv_layer<128, 128, 9, true, false, false>(lds, img, local, H1, 128,
            WH + w0 + 479232, BS + b0 + 480, H2, 128, nullptr, 1.f);
        img_barrier(bar, img, ++gen * 32u);
        conv_layer<128, 96, 9, false, true, false>(lds, img, local, H2, 128,
            WH + w0 + 626688, BS + b0 + 608, cur + 96, 192, nullptr, 1.f);
        img_barrier(bar, img, ++gen * 32u);
        if (blk < 31)
            conv_layer<192, 192, 1, false, false, false>(lds, img, local, cur, 192,
                MH + (size_t)blk * 36864, nullptr, nxt, 192, nullptr, 0.5f);
        else
            conv_layer<192, 192, 1, false, false, true>(lds, img, local, cur, 192,
                MH + (size_t)blk * 36864, nullptr, nullptr, 192, out,
                2147483648.f /* 2^31 */);
        img_barrier(bar, img, ++gen * 32u);
    }
}

// ---------------------------------------------------------------------------
extern "C" void kernel_launch(void* const* d_in, const int* in_sizes, int n_in,
                              void* d_out, int out_size, void* d_ws, size_t ws_size,
                              hipStream_t stream)
{
    const float* x     = (const float*)d_in[0];
    const float* mu    = (const float*)d_in[1];
    const float* sigma = (const float*)d_in[2];
    const float* wf    = (const float*)d_in[3];
    const float* bf    = (const float*)d_in[4];
    const float* mf    = (const float*)d_in[5];
    const int*   perm  = (const int*)d_in[6];
    float*       out   = (float*)d_out;

    char* ws = (char*)d_ws;
    f16*      WH  = (f16*)(ws);                  // 47,185,920 B
    f16*      MH  = (f16*)(ws + 47185920);       //  2,359,296 B
    float*    BS  = (float*)(ws + 49545216);     //     90,112 B
    f16*      XA  = (f16*)(ws + 49635328);       //  3,145,728 B
    f16*      XB  = (f16*)(ws + 52781056);       //  3,145,728 B
    f16*      H1  = (f16*)(ws + 55926784);       //  2,097,152 B
    f16*      H2  = (f16*)(ws + 58023936);       //  2,097,152 B
    unsigned* BAR = (unsigned*)(ws + 60121088);  //      4,096 B

    hipMemsetAsync(BAR, 0, 4096, stream);

    wconv_k<<<dim3(64, 192), TPB, 0, stream>>>(wf, WH);
    mconv_k<<<dim3(4608), TPB, 0, stream>>>(mf, MH, 1179648);
    bconv_k<<<dim3(88),   TPB, 0, stream>>>(bf, BS, 22528);
    prologue_k<<<dim3(6144), TPB, 0, stream>>>(x, mu, sigma, perm, XA);

    constexpr int LDSB = 61440;  // max over layers (mix: 49152 X + 12288 W)
    persist_k<<<dim3(256), TPB, LDSB, stream>>>(WH, MH, BS, XA, XB, H1, H2, out, BAR);
}

// Round 3
// 3709.013 us; speedup vs baseline: 1.0024x; 1.0024x over previous
//
#include <hip/hip_runtime.h>

typedef _Float16 f16;
typedef _Float16 f16x8 __attribute__((ext_vector_type(8)));
typedef _Float16 f16x4 __attribute__((ext_vector_type(4)));
typedef float    f32x4 __attribute__((ext_vector_type(4)));

// async global->LDS DMA, 16B per lane, dest = uniform base + lane*16
#define GLOAD16(gp, lp) __builtin_amdgcn_global_load_lds(                      \
    (const __attribute__((address_space(1))) void*)(gp),                       \
    (__attribute__((address_space(3))) void*)(lp), 16, 0, 0)

// ---------------------------------------------------------------------------
// Prologue: normalize -> per-channel pixel permutation -> space_to_depth.
// Out: XA[p][c] fp16, p = img*1024 + h2*32 + w2, c = 0..191. 8 ch per thread.
// ---------------------------------------------------------------------------
__global__ __launch_bounds__(256) void prologue_k(
    const float* __restrict__ x, const float* __restrict__ mu,
    const float* __restrict__ sigma, const int* __restrict__ perm,
    f16* __restrict__ A0)
{
    int gid = blockIdx.x * 256 + threadIdx.x;
    if (gid >= 8192 * 24) return;
    int c8 = gid % 24;
    int p  = gid / 24;
    int b  = p >> 10;
    int h2 = (p >> 5) & 31;
    int w2 = p & 31;
    int cc = c8 >> 3;          // source channel
    int bh = c8 & 7;
    const int* pm = &perm[cc * 65536 + (h2 * 8 + bh) * 256 + w2 * 8];
    const float* xp = &x[(b * 3 + cc) * 65536];
    float m = mu[cc], rs = 1.0f / sigma[cc];
    f16 v[8];
#pragma unroll
    for (int k = 0; k < 8; ++k)
        v[k] = (f16)((xp[pm[k]] - m) * rs);
    *(f16x8*)&A0[(size_t)p * 192 + c8 * 8] = *(f16x8*)v;
}

// ---------------------------------------------------------------------------
// Weight conversion: fp32 [oc][ic][3][3] -> fp16 [tap][c8][oc][8] per conv.
// Thread <-> (c8, o): reads 72 contiguous floats, writes 9 coalesced f16x8.
// ---------------------------------------------------------------------------
__global__ __launch_bounds__(256) void wconv_k(const float* __restrict__ wf,
                                               f16* __restrict__ wh)
{
    int c   = blockIdx.y;          // conv 0..191
    int s   = c % 6;
    int s3  = s % 3;
    int icr = (s3 == 0) ? 96 : 128;
    int ocv = (s3 == 2) ? 96 : 128;
    int nc8 = icr >> 3;
    int wo  = (s3 == 0 ? 0 : (s3 == 1 ? 110592 : 258048)) + (s >= 3 ? 368640 : 0);
    int idx = blockIdx.x * 256 + threadIdx.x;
    if (idx >= nc8 * ocv) return;
    int o  = idx % ocv;
    int c8 = idx / ocv;
    size_t base = (size_t)(c / 6) * 737280 + wo;
    const float* src = &wf[base + ((size_t)o * icr + c8 * 8) * 9];
    f16 vt[9][8];
#pragma unroll
    for (int k = 0; k < 8; ++k)
#pragma unroll
        for (int t = 0; t < 9; ++t)
            vt[t][k] = (f16)src[k * 9 + t];
#pragma unroll
    for (int t = 0; t < 9; ++t)
        *(f16x8*)&wh[base + ((size_t)(t * nc8 + c8) * ocv + o) * 8] = *(f16x8*)vt[t];
}

// m fp32 [mat][o][i] -> fp16 [mat][i8][o][8]
__global__ __launch_bounds__(256) void mconv_k(const float* __restrict__ mf,
                                               f16* __restrict__ mh)
{
    int n = blockIdx.x * 256 + threadIdx.x;
    if (n >= 32 * 24 * 192) return;
    int o   = n % 192;
    int t   = n / 192;
    int i8  = t % 24;
    int mat = t / 24;
    const float* s = &mf[(size_t)mat * 36864 + o * 192 + i8 * 8];
    f16 v[8];
#pragma unroll
    for (int k = 0; k < 8; ++k) v[k] = (f16)s[k];
    *(f16x8*)&mh[(size_t)mat * 36864 + ((size_t)i8 * 192 + o) * 8] = *(f16x8*)v;
}

// biases fp32, pre-scaled by 2^-block (704 per block)
__global__ __launch_bounds__(256) void bconv_k(const float* __restrict__ bf,
                                               float* __restrict__ bs, int n)
{
    int i = blockIdx.x * 256 + threadIdx.x;
    if (i < n) bs[i] = ldexpf(bf[i], -(i / 704));
}

// ---------------------------------------------------------------------------
// Conv / mix layer. 1-row px tiles (32 px), WG = 2 waves (oc-split), chunked
// K (64 ch per chunk), X+W double-buffered via global_load_lds, one raw
// barrier + vmcnt(0) per (chunk,tap) step. XOR bank swizzle on X.
//   OCW  : oc per wave (32 or 48)        OCV  : total OC of this conv
//   NC8R : real 8-ch granules of IC (12/16/24); padded to CHN*8 with zero W
// ---------------------------------------------------------------------------
template<int OCW, int OCV, int NC8R, int TAPS, bool RELU, bool ACCUM, bool OUT32>
__global__ __launch_bounds__(128) void conv_k(
    const f16* __restrict__ Xin, int ICS,
    const f16* __restrict__ W, const float* __restrict__ bias,
    f16* __restrict__ Out, int OCS, float* __restrict__ Out32, float scale)
{
    constexpr int PAD   = (TAPS == 9) ? 1 : 0;
    constexpr int ROWS  = 1 + 2 * PAD;            // 3 or 1
    constexpr int WW    = 32 + 2 * PAD;           // 34 or 32
    constexpr int CHN   = (NC8R + 7) / 8;         // 64-ch chunks
    constexpr int OCW2  = 2 * OCW;
    constexpr int MM    = OCW / 16;
    constexpr int XSLOT = ROWS * WW * 8;          // 16B slots per X buffer
    constexpr int XB_   = XSLOT * 16;
    constexpr int WSLOT = 8 * OCW2;
    constexpr int WB_   = WSLOT * 16;

    extern __shared__ char lds[];                 // [X0][X1][W0][W1]

    const int tid  = threadIdx.x;
    const int lane = tid & 63, wave = tid >> 6;
    const int lq   = lane >> 4, ln = lane & 15;
    const int tile = blockIdx.x;                  // 256 = img*32 + row
    const int img  = tile >> 5, row = tile & 31;
    const int ocg  = blockIdx.y * OCW2;

    // ---- stage X chunk (swizzled source assignment, zero halo) ----
    auto issueX = [&](int chunk, int par) {
        char* xb = lds + par * XB_;
        const int ch0 = chunk * 64;
        for (int inst = wave; inst * 64 < XSLOT; inst += 2) {
            int s   = inst * 64 + lane;
            int c8p = s & 7;
            int wr  = s >> 3;
            int wv  = wr % WW;
            int ri  = wr / WW;
            int r   = row - PAD + ri;
            int cl  = wv - PAD;
            bool inb = (s < XSLOT) & ((unsigned)r < 32u) & ((unsigned)cl < 32u);
            if (inb) {
                int ch = ch0 + ((c8p ^ (wv & 7)) << 3);
                const f16* g = &Xin[(size_t)(img * 1024 + r * 32 + cl) * ICS + ch];
                GLOAD16(g, xb + inst * 1024);
            } else if (s < XSLOT) {
                *(f16x8*)(xb + (size_t)s * 16) = (f16x8){};
            }
        }
    };

    // ---- stage W slice (tap, chunk): [c8][ocL][8]; zero padded granules ----
    auto issueW = [&](int chunk, int tap, int par) {
        char* wb = lds + 2 * XB_ + par * WB_;
        for (int inst = wave; inst * 64 < WSLOT; inst += 2) {
            int s     = inst * 64 + lane;
            int c8l   = s / OCW2;
            int ocL   = s - c8l * OCW2;
            int c8abs = chunk * 8 + c8l;
            if (c8abs < NC8R) {
                const f16* g = &W[((size_t)(tap * NC8R + c8abs) * OCV + ocg + ocL) * 8];
                GLOAD16(g, wb + inst * 1024);
            } else {
                *(f16x8*)(wb + (size_t)s * 16) = (f16x8){};
            }
        }
    };

    issueX(0, 0);
    issueW(0, 0, 0);

    f32x4 acc[MM][2] = {};
    int wpar = 0;

    for (int chunk = 0; chunk < CHN; ++chunk) {
#pragma unroll
        for (int tap = 0; tap < TAPS; ++tap) {
            asm volatile("s_waitcnt vmcnt(0) lgkmcnt(0)" ::: "memory");
            __builtin_amdgcn_s_barrier();
            asm volatile("" ::: "memory");
            // prefetch next step's operands (in flight during MFMAs)
            {
                int ntap = tap + 1, nch = chunk;
                if (ntap == TAPS) { ntap = 0; nch++; }
                if (nch < CHN) {
                    if (ntap == 0) issueX(nch, nch & 1);
                    issueW(nch, ntap, wpar ^ 1);
                }
            }
            const int dy = (TAPS == 9) ? tap / 3 - 1 : 0;
            const int dx = (TAPS == 9) ? tap % 3 - 1 : 0;
            const char* xb = lds + (chunk & 1) * XB_;
            const char* wb = lds + 2 * XB_ + wpar * WB_;
#pragma unroll
            for (int kc = 0; kc < 2; ++kc) {
                const int kcg = kc * 4 + lq;
                f16x8 a[MM], b[2];
#pragma unroll
                for (int m = 0; m < MM; ++m)
                    a[m] = *(const f16x8*)(wb +
                        (size_t)(kcg * OCW2 + wave * OCW + m * 16 + ln) * 16);
#pragma unroll
                for (int n = 0; n < 2; ++n) {
                    int wv = n * 16 + ln + PAD + dx;
                    b[n] = *(const f16x8*)(xb +
                        (size_t)(((PAD + dy) * WW + wv) * 8 + (kcg ^ (wv & 7))) * 16);
                }
#pragma unroll
                for (int m = 0; m < MM; ++m)
#pragma unroll
                    for (int n = 0; n < 2; ++n)
                        acc[m][n] = __builtin_amdgcn_mfma_f32_16x16x32_f16(
                            a[m], b[n], acc[m][n], 0, 0, 0);
            }
            wpar ^= 1;
        }
    }

    // ---- epilogue ----
#pragma unroll
    for (int m = 0; m < MM; ++m) {
        const int oc = ocg + wave * OCW + m * 16 + lq * 4;
        float b0 = 0.f, b1 = 0.f, b2 = 0.f, b3 = 0.f;
        if (TAPS == 9) {
            float4 bv = *(const float4*)&bias[oc];
            b0 = bv.x; b1 = bv.y; b2 = bv.z; b3 = bv.w;
        }
#pragma unroll
        for (int n = 0; n < 2; ++n) {
            float v0 = acc[m][n][0] * scale + b0;
            float v1 = acc[m][n][1] * scale + b1;
            float v2 = acc[m][n][2] * scale + b2;
            float v3 = acc[m][n][3] * scale + b3;
            if (RELU) {
                v0 = fmaxf(v0, 0.f); v1 = fmaxf(v1, 0.f);
                v2 = fmaxf(v2, 0.f); v3 = fmaxf(v3, 0.f);
            }
            if (OUT32) {
                size_t ob = (size_t)(img * 192 + oc) * 1024 + row * 32 + n * 16 + ln;
                Out32[ob]          = v0;
                Out32[ob + 1024]   = v1;
                Out32[ob + 2048]   = v2;
                Out32[ob + 3072]   = v3;
            } else {
                const int p = img * 1024 + row * 32 + n * 16 + ln;
                f16* op = &Out[(size_t)p * OCS + oc];
                if (ACCUM) {
                    f16x4 old = *(const f16x4*)op;
                    v0 += (float)old[0]; v1 += (float)old[1];
                    v2 += (float)old[2]; v3 += (float)old[3];
                }
                f16x4 hv;
                hv[0] = (f16)v0; hv[1] = (f16)v1; hv[2] = (f16)v2; hv[3] = (f16)v3;
                *(f16x4*)op = hv;
            }
        }
    }
}

// ---------------------------------------------------------------------------
extern "C" void kernel_launch(void* const* d_in, const int* in_sizes, int n_in,
                              void* d_out, int out_size, void* d_ws, size_t ws_size,
                              hipStream_t stream)
{
    const float* x     = (const float*)d_in[0];
    const float* mu    = (const float*)d_in[1];
    const float* sigma = (const float*)d_in[2];
    const float* wf    = (const float*)d_in[3];
    const float* bf    = (const float*)d_in[4];
    const float* mf    = (const float*)d_in[5];
    const int*   perm  = (const int*)d_in[6];
    float*       out   = (float*)d_out;

    char* ws = (char*)d_ws;
    f16*   WH = (f16*)(ws);                  // 47,185,920 B
    f16*   MH = (f16*)(ws + 47185920);       //  2,359,296 B
    float* BS = (float*)(ws + 49545216);     //     90,112 B
    f16*   XA = (f16*)(ws + 49635328);       //  3,145,728 B
    f16*   XB = (f16*)(ws + 52781056);       //  3,145,728 B
    f16*   H1 = (f16*)(ws + 55926784);       //  2,097,152 B
    f16*   H2 = (f16*)(ws + 58023936);       //  2,097,152 B

    wconv_k   <<<dim3(8, 192), 256, 0, stream>>>(wf, WH);
    mconv_k   <<<dim3(576),    256, 0, stream>>>(mf, MH);
    bconv_k   <<<dim3(88),     256, 0, stream>>>(bf, BS, 22528);
    prologue_k<<<dim3(768),    256, 0, stream>>>(x, mu, sigma, perm, XA);

    constexpr int LDS_C12 = 2 * 13056 + 2 * 8192;   // 42,496 B
    constexpr int LDS_C3  = 2 * 13056 + 2 * 12288;  // 50,688 B
    constexpr int LDS_MIX = 2 * 4096  + 2 * 8192;   // 24,576 B

    for (int blk = 0; blk < 32; ++blk) {
        size_t w0 = (size_t)blk * 737280;
        size_t b0 = (size_t)blk * 704;
        f16* cur = (blk & 1) ? XB : XA;
        f16* nxt = (blk & 1) ? XA : XB;
        // round 1: chain(half1) -> accumulate into half0
        conv_k<32, 128, 12, 9, true,  false, false><<<dim3(256, 2), 128, LDS_C12, stream>>>(
            cur + 96, 192, WH + w0 + 0,      BS + b0 + 0,   H1, 128, nullptr, 1.f);
        conv_k<32, 128, 16, 9, true,  false, false><<<dim3(256, 2), 128, LDS_C12, stream>>>(
            H1, 128,       WH + w0 + 110592, BS + b0 + 128, H2, 128, nullptr, 1.f);
        conv_k<48,  96, 16, 9, false, true,  false><<<dim3(256, 1), 128, LDS_C3, stream>>>(
            H2, 128,       WH + w0 + 258048, BS + b0 + 256, cur, 192, nullptr, 1.f);
        // round 2: chain(half0) -> accumulate into half1
        conv_k<32, 128, 12, 9, true,  false, false><<<dim3(256, 2), 128, LDS_C12, stream>>>(
            cur, 192,      WH + w0 + 368640, BS + b0 + 352, H1, 128, nullptr, 1.f);
        conv_k<32, 128, 16, 9, true,  false, false><<<dim3(256, 2), 128, LDS_C12, stream>>>(
            H1, 128,       WH + w0 + 479232, BS + b0 + 480, H2, 128, nullptr, 1.f);
        conv_k<48,  96, 16, 9, false, true,  false><<<dim3(256, 1), 128, LDS_C3, stream>>>(
            H2, 128,       WH + w0 + 626688, BS + b0 + 608, cur + 96, 192, nullptr, 1.f);
        // mix (0.5 rescale; final: 2^31 un-scale + fp32 out)
        if (blk < 31)
            conv_k<32, 192, 24, 1, false, false, false><<<dim3(256, 3), 128, LDS_MIX, stream>>>(
                cur, 192, MH + (size_t)blk * 36864, nullptr, nxt, 192, nullptr, 0.5f);
        else
            conv_k<32, 192, 24, 1, false, false, true><<<dim3(256, 3), 128, LDS_MIX, stream>>>(
                cur, 192, MH + (size_t)blk * 36864, nullptr, nullptr, 192, out,
                2147483648.f /* 2^31 */);
    }
}

// Round 4
// 2781.715 us; speedup vs baseline: 1.3365x; 1.3334x over previous
//
#include <hip/hip_runtime.h>

typedef _Float16 f16;
typedef _Float16 f16x8 __attribute__((ext_vector_type(8)));
typedef _Float16 f16x4 __attribute__((ext_vector_type(4)));
typedef float    f32x4 __attribute__((ext_vector_type(4)));

// async global->LDS DMA, 16B per lane: dest = uniform base + lane*16
#define GLOAD16(gp, lp) __builtin_amdgcn_global_load_lds(                      \
    (const __attribute__((address_space(1))) void*)(gp),                       \
    (__attribute__((address_space(3))) void*)(lp), 16, 0, 0)

// ---------------------------------------------------------------------------
// Prologue: normalize -> per-channel pixel permutation -> space_to_depth.
// Out: XA[p][c] fp16, p = img*1024 + h2*32 + w2, c = 0..191.
// ---------------------------------------------------------------------------
__global__ __launch_bounds__(256) void prologue_k(
    const float* __restrict__ x, const float* __restrict__ mu,
    const float* __restrict__ sigma, const int* __restrict__ perm,
    f16* __restrict__ A0)
{
    int gid = blockIdx.x * 256 + threadIdx.x;
    if (gid >= 8192 * 24) return;
    int c8 = gid % 24;
    int p  = gid / 24;
    int b  = p >> 10;
    int h2 = (p >> 5) & 31;
    int w2 = p & 31;
    int cc = c8 >> 3;
    int bh = c8 & 7;
    const int* pm = &perm[cc * 65536 + (h2 * 8 + bh) * 256 + w2 * 8];
    const float* xp = &x[(b * 3 + cc) * 65536];
    float m = mu[cc], rs = 1.0f / sigma[cc];
    f16 v[8];
#pragma unroll
    for (int k = 0; k < 8; ++k)
        v[k] = (f16)((xp[pm[k]] - m) * rs);
    *(f16x8*)&A0[(size_t)p * 192 + c8 * 8] = *(f16x8*)v;
}

// ---------------------------------------------------------------------------
// Weight conversion: fp32 [oc][ic][3][3] -> fp16 [tap][c8][oc][8] per conv.
// ---------------------------------------------------------------------------
__global__ __launch_bounds__(256) void wconv_k(const float* __restrict__ wf,
                                               f16* __restrict__ wh)
{
    int c   = blockIdx.y;          // conv 0..191
    int s   = c % 6;
    int s3  = s % 3;
    int icr = (s3 == 0) ? 96 : 128;
    int ocv = (s3 == 2) ? 96 : 128;
    int nc8 = icr >> 3;
    int wo  = (s3 == 0 ? 0 : (s3 == 1 ? 110592 : 258048)) + (s >= 3 ? 368640 : 0);
    int idx = blockIdx.x * 256 + threadIdx.x;
    if (idx >= nc8 * ocv) return;
    int o  = idx % ocv;
    int c8 = idx / ocv;
    size_t base = (size_t)(c / 6) * 737280 + wo;
    const float* src = &wf[base + ((size_t)o * icr + c8 * 8) * 9];
    f16 vt[9][8];
#pragma unroll
    for (int k = 0; k < 8; ++k)
#pragma unroll
        for (int t = 0; t < 9; ++t)
            vt[t][k] = (f16)src[k * 9 + t];
#pragma unroll
    for (int t = 0; t < 9; ++t)
        *(f16x8*)&wh[base + ((size_t)(t * nc8 + c8) * ocv + o) * 8] = *(f16x8*)vt[t];
}

// m fp32 [mat][o][i] -> fp16 [mat][i8][o][8]
__global__ __launch_bounds__(256) void mconv_k(const float* __restrict__ mf,
                                               f16* __restrict__ mh)
{
    int n = blockIdx.x * 256 + threadIdx.x;
    if (n >= 32 * 24 * 192) return;
    int o   = n % 192;
    int t   = n / 192;
    int i8  = t % 24;
    int mat = t / 24;
    const float* s = &mf[(size_t)mat * 36864 + o * 192 + i8 * 8];
    f16 v[8];
#pragma unroll
    for (int k = 0; k < 8; ++k) v[k] = (f16)s[k];
    *(f16x8*)&mh[(size_t)mat * 36864 + ((size_t)i8 * 192 + o) * 8] = *(f16x8*)v;
}

// biases fp32, pre-scaled by 2^-block (704 per block)
__global__ __launch_bounds__(256) void bconv_k(const float* __restrict__ bf,
                                               float* __restrict__ bs, int n)
{
    int i = blockIdx.x * 256 + threadIdx.x;
    if (i < n) bs[i] = ldexpf(bf[i], -(i / 704));
}

// ---------------------------------------------------------------------------
// Conv / mix layer.
//   - Weights: global -> VGPR directly (no LDS), double-buffered 1 tap ahead.
//   - X: staged to LDS ONCE (full IC, pow2-padded granule stride, XOR swizzle
//     applied via pre-swizzled DMA source). ONE __syncthreads per dispatch.
//   - WG = 128 threads (2 waves); wave covers OCW=MMv*16 oc x 32 px.
//   MMv: A-tiles per wave. OCV: conv OC. NC8R: real IC/8 (12/16/24).
// ---------------------------------------------------------------------------
template<int MMv, int OCV, int NC8R, int TAPS, bool RELU, bool ACCUM, bool OUT32>
__global__ __launch_bounds__(128) void conv_k(
    const f16* __restrict__ Xin, int ICS,
    const f16* __restrict__ W, const float* __restrict__ bias,
    f16* __restrict__ Out, int OCS, float* __restrict__ Out32, float scale)
{
    constexpr int PAD   = (TAPS == 9) ? 1 : 0;
    constexpr int ROWS  = 1 + 2 * PAD;            // 3 or 1
    constexpr int WW    = 32 + 2 * PAD;           // 34 or 32
    constexpr int NC8P  = (TAPS == 9) ? 16 : 32;  // padded granule stride (pow2)
    constexpr int SWM   = NC8P - 1;
    constexpr int KC    = NC8R / 4;               // K32 chunks (3/4/6)
    constexpr int OCW   = MMv * 16;
    constexpr int SLOTS = ROWS * WW * NC8P;       // 16B granules in LDS

    __shared__ f16 xs[SLOTS * 8];

    const int tid  = threadIdx.x;
    const int lane = tid & 63, wave = tid >> 6;
    const int lq   = lane >> 4, ln = lane & 15;
    const int img  = blockIdx.x >> 5, row = blockIdx.x & 31;
    const int ocg  = blockIdx.y * (2 * OCW) + wave * OCW;

    // ---- stage X (whole IC, one shot; swizzled source; zeroed halo) ----
    for (int s0 = wave * 64; s0 < SLOTS; s0 += 128) {
        int s   = s0 + lane;
        int c8s = s & SWM;
        int wr  = s >> ((NC8P == 16) ? 4 : 5);
        int wv  = wr % WW;
        int ri  = wr / WW;
        int c8  = c8s ^ (wv & SWM);               // source granule for this slot
        int r   = row - PAD + ri;
        int cl  = wv - PAD;
        bool live = (s < SLOTS) && (c8 < NC8R);
        bool inb  = ((unsigned)r < 32u) && ((unsigned)cl < 32u);
        if (live && inb) {
            GLOAD16(&Xin[(size_t)(img * 1024 + r * 32 + cl) * ICS + c8 * 8],
                    (char*)xs + (size_t)s0 * 16);
        } else if (live) {
            *(f16x8*)&xs[(size_t)s * 8] = (f16x8){};   // halo zeros
        }
    }

    // ---- W loader: tap slice -> named register buffer (static idx only) ----
    auto loadw = [&](f16x8 (&wr_)[KC][MMv], int tap) {
#pragma unroll
        for (int kc = 0; kc < KC; ++kc)
#pragma unroll
            for (int m = 0; m < MMv; ++m)
                wr_[kc][m] = *(const f16x8*)&W[
                    ((size_t)(tap * NC8R + kc * 4 + lq) * OCV + ocg + m * 16 + ln) * 8];
    };

    f16x8 w0[KC][MMv], w1[KC][MMv];
    loadw(w0, 0);

    asm volatile("s_waitcnt vmcnt(0) lgkmcnt(0)" ::: "memory");
    __syncthreads();   // X fully staged; only barrier in the kernel

    f32x4 acc[MMv][2] = {};

#pragma unroll
    for (int tap = 0; tap < TAPS; ++tap) {
        const int dy = (TAPS == 9) ? tap / 3 - 1 : 0;
        const int dx = (TAPS == 9) ? tap % 3 - 1 : 0;
        // prefetch next tap's weights (flight hides under this tap's MFMAs)
        if (tap + 1 < TAPS) {
            if (tap & 1) loadw(w0, tap + 1);
            else         loadw(w1, tap + 1);
        }
#pragma unroll
        for (int kc = 0; kc < KC; ++kc) {
            const int kcg = kc * 4 + lq;
            f16x8 b[2];
#pragma unroll
            for (int n = 0; n < 2; ++n) {
                int wv = n * 16 + ln + PAD + dx;
                b[n] = *(const f16x8*)&xs[
                    (size_t)(((PAD + dy) * WW + wv) * NC8P + (kcg ^ (wv & SWM))) * 8];
            }
#pragma unroll
            for (int m = 0; m < MMv; ++m) {
                const f16x8& a = (tap & 1) ? w1[kc][m] : w0[kc][m];
#pragma unroll
                for (int n = 0; n < 2; ++n)
                    acc[m][n] = __builtin_amdgcn_mfma_f32_16x16x32_f16(
                        a, b[n], acc[m][n], 0, 0, 0);
            }
        }
    }

    // ---- epilogue ----
#pragma unroll
    for (int m = 0; m < MMv; ++m) {
        const int oc = ocg + m * 16 + lq * 4;
        float b0 = 0.f, b1 = 0.f, b2 = 0.f, b3 = 0.f;
        if (TAPS == 9) {
            float4 bv = *(const float4*)&bias[oc];
            b0 = bv.x; b1 = bv.y; b2 = bv.z; b3 = bv.w;
        }
#pragma unroll
        for (int n = 0; n < 2; ++n) {
            float v0 = acc[m][n][0] * scale + b0;
            float v1 = acc[m][n][1] * scale + b1;
            float v2 = acc[m][n][2] * scale + b2;
            float v3 = acc[m][n][3] * scale + b3;
            if (RELU) {
                v0 = fmaxf(v0, 0.f); v1 = fmaxf(v1, 0.f);
                v2 = fmaxf(v2, 0.f); v3 = fmaxf(v3, 0.f);
            }
            if (OUT32) {
                size_t ob = (size_t)(img * 192 + oc) * 1024 + row * 32 + n * 16 + ln;
                Out32[ob]        = v0;
                Out32[ob + 1024] = v1;
                Out32[ob + 2048] = v2;
                Out32[ob + 3072] = v3;
            } else {
                const int p = img * 1024 + row * 32 + n * 16 + ln;
                f16* op = &Out[(size_t)p * OCS + oc];
                if (ACCUM) {
                    f16x4 old = *(const f16x4*)op;
                    v0 += (float)old[0]; v1 += (float)old[1];
                    v2 += (float)old[2]; v3 += (float)old[3];
                }
                f16x4 hv;
                hv[0] = (f16)v0; hv[1] = (f16)v1; hv[2] = (f16)v2; hv[3] = (f16)v3;
                *(f16x4*)op = hv;
            }
        }
    }
}

// ---------------------------------------------------------------------------
extern "C" void kernel_launch(void* const* d_in, const int* in_sizes, int n_in,
                              void* d_out, int out_size, void* d_ws, size_t ws_size,
                              hipStream_t stream)
{
    const float* x     = (const float*)d_in[0];
    const float* mu    = (const float*)d_in[1];
    const float* sigma = (const float*)d_in[2];
    const float* wf    = (const float*)d_in[3];
    const float* bf    = (const float*)d_in[4];
    const float* mf    = (const float*)d_in[5];
    const int*   perm  = (const int*)d_in[6];
    float*       out   = (float*)d_out;

    char* ws = (char*)d_ws;
    f16*   WH = (f16*)(ws);                  // 47,185,920 B
    f16*   MH = (f16*)(ws + 47185920);       //  2,359,296 B
    float* BS = (float*)(ws + 49545216);     //     90,112 B
    f16*   XA = (f16*)(ws + 49635328);       //  3,145,728 B
    f16*   XB = (f16*)(ws + 52781056);       //  3,145,728 B
    f16*   H1 = (f16*)(ws + 55926784);       //  2,097,152 B
    f16*   H2 = (f16*)(ws + 58023936);       //  2,097,152 B

    wconv_k   <<<dim3(8, 192), 256, 0, stream>>>(wf, WH);
    mconv_k   <<<dim3(576),    256, 0, stream>>>(mf, MH);
    bconv_k   <<<dim3(88),     256, 0, stream>>>(bf, BS, 22528);
    prologue_k<<<dim3(768),    256, 0, stream>>>(x, mu, sigma, perm, XA);

    for (int blk = 0; blk < 32; ++blk) {
        size_t w0 = (size_t)blk * 737280;
        size_t b0 = (size_t)blk * 704;
        f16* cur = (blk & 1) ? XB : XA;
        f16* nxt = (blk & 1) ? XA : XB;
        // round 1: chain(half1) -> accumulate into half0
        conv_k<2, 128, 12, 9, true,  false, false><<<dim3(256, 2), 128, 0, stream>>>(
            cur + 96, 192, WH + w0 + 0,      BS + b0 + 0,   H1, 128, nullptr, 1.f);
        conv_k<2, 128, 16, 9, true,  false, false><<<dim3(256, 2), 128, 0, stream>>>(
            H1, 128,       WH + w0 + 110592, BS + b0 + 128, H2, 128, nullptr, 1.f);
        conv_k<3,  96, 16, 9, false, true,  false><<<dim3(256, 1), 128, 0, stream>>>(
            H2, 128,       WH + w0 + 258048, BS + b0 + 256, cur, 192, nullptr, 1.f);
        // round 2: chain(half0) -> accumulate into half1
        conv_k<2, 128, 12, 9, true,  false, false><<<dim3(256, 2), 128, 0, stream>>>(
            cur, 192,      WH + w0 + 368640, BS + b0 + 352, H1, 128, nullptr, 1.f);
        conv_k<2, 128, 16, 9, true,  false, false><<<dim3(256, 2), 128, 0, stream>>>(
            H1, 128,       WH + w0 + 479232, BS + b0 + 480, H2, 128, nullptr, 1.f);
        conv_k<3,  96, 16, 9, false, true,  false><<<dim3(256, 1), 128, 0, stream>>>(
            H2, 128,       WH + w0 + 626688, BS + b0 + 608, cur + 96, 192, nullptr, 1.f);
        // mix (0.5 rescale; final: 2^31 un-scale + fp32 out)
        if (blk < 31)
            conv_k<2, 192, 24, 1, false, false, false><<<dim3(256, 3), 128, 0, stream>>>(
                cur, 192, MH + (size_t)blk * 36864, nullptr, nxt, 192, nullptr, 0.5f);
        else
            conv_k<2, 192, 24, 1, false, false, true><<<dim3(256, 3), 128, 0, stream>>>(
                cur, 192, MH + (size_t)blk * 36864, nullptr, nullptr, 192, out,
                2147483648.f /* 2^31 */);
    }
}